// Round 4
// baseline (31138.602 us; speedup 1.0000x reference)
//
#include <hip/hip_runtime.h>

// Problem constants (from reference)
#define BB    2048
#define TT    100
#define CC    8
#define HD    64
#define HHD   128
#define OO    10
#define MROWS 8      // batch rows per block; grid = 256 blocks = 1 block/CU
#define NTHR  512    // 8 waves/block

__device__ __forceinline__ float fast_tanh(float x) {
  float e = __expf(2.0f * x);
  return 1.0f - 2.0f / (e + 1.0f);
}

__global__ void zero_out_k(float* o) {
  if (threadIdx.x < 2) o[threadIdx.x] = 0.0f;
}

// Hidden layer k-slice, weights STREAMED from global (L2-hot, short-lived regs):
// wave wv owns k in [16wv,16wv+16), lane l owns cols (l, l+64).
// Reads pin (pre-activation+bias) with relu applied inline; ds_add into pout.
__device__ __forceinline__ void hidden_adds_g(const float* __restrict__ Wg,
                                              const float (*pin)[HHD],
                                              float (*pout)[HHD],
                                              int l, int wv) {
  const int kb = 16 * wv;
  float wx[16], wy[16];                       // 32 regs, live only in this phase
#pragma unroll
  for (int j = 0; j < 16; ++j) {
    const float* wr = Wg + (kb + j) * HHD;
    wx[j] = wr[l];                            // coalesced 256B per wave
    wy[j] = wr[l + 64];
  }
#pragma unroll
  for (int r = 0; r < MROWS; ++r) {
    const float4 h0 = *(const float4*)&pin[r][kb + 0];   // wave-uniform -> broadcast
    const float4 h1 = *(const float4*)&pin[r][kb + 4];
    const float4 h2 = *(const float4*)&pin[r][kb + 8];
    const float4 h3 = *(const float4*)&pin[r][kb + 12];
    const float hk[16] = {
      fmaxf(h0.x,0.f), fmaxf(h0.y,0.f), fmaxf(h0.z,0.f), fmaxf(h0.w,0.f),
      fmaxf(h1.x,0.f), fmaxf(h1.y,0.f), fmaxf(h1.z,0.f), fmaxf(h1.w,0.f),
      fmaxf(h2.x,0.f), fmaxf(h2.y,0.f), fmaxf(h2.z,0.f), fmaxf(h2.w,0.f),
      fmaxf(h3.x,0.f), fmaxf(h3.y,0.f), fmaxf(h3.z,0.f), fmaxf(h3.w,0.f) };
    float a0 = 0.f, a1 = 0.f;
#pragma unroll
    for (int k = 0; k < 16; ++k) {
      a0 = fmaf(hk[k], wx[k], a0);
      a1 = fmaf(hk[k], wy[k], a1);
    }
    atomicAdd(&pout[r][l],      a0);          // ds_add_f32, 2-way bank alias = free
    atomicAdd(&pout[r][l + 64], a1);
  }
}

__global__ void __launch_bounds__(NTHR)
cde_main(const float* __restrict__ coeffs, const int* __restrict__ yy,
         const float* __restrict__ times,
         const float* __restrict__ W_init, const float* __restrict__ b_init,
         const float* __restrict__ W_in,  const float* __restrict__ b_in,
         const float* __restrict__ W_h,   const float* __restrict__ b_h,
         const float* __restrict__ W_out, const float* __restrict__ b_out,
         const float* __restrict__ W_read,const float* __restrict__ b_read,
         float* __restrict__ out)
{
  __shared__ float sZs[MROWS][HD];        // 2KB   stage-input z
  __shared__ float pA [MROWS][HHD];       // 4KB   bias-primed partials, layer A
  __shared__ float p1 [MROWS][HHD];       // 4KB   hidden1
  __shared__ float p2 [MROWS][HHD];       // 4KB   hidden2
  __shared__ float pB [MROWS][576];       // 18KB  big layer, addr = col + (col>>3)
  __shared__ float sDx[MROWS][CC];
  __shared__ float sLog[MROWS][OO];

  const int t    = threadIdx.x;
  const int wv   = t >> 6;        // wave id 0..7 (k-slice owner; epilogue row)
  const int l    = t & 63;        // lane         (col owner; epilogue h)
  const int row0 = blockIdx.x * MROWS;

  // tiny resident scalars only (compiler keeps these happily)
  const float binx = b_in[l],        biny = b_in[l + 64];
  const float b1x  = b_h[l],         b1y  = b_h[l + 64];
  const float b2x  = b_h[HHD + l],   b2y  = b_h[HHD + l + 64];
  const float boutv = b_out[t];

  // ---- z0 ; thread owns (row wv, h=l) ----
  float z0, kacc = 0.f;
  {
    const float* cf = coeffs + (size_t)(row0 + wv) * (TT*CC);
    float a = b_init[l];
#pragma unroll
    for (int c = 0; c < CC; ++c) a = fmaf(cf[c], W_init[c*HD + l], a);
    z0 = a;
    sZs[wv][l] = a;
  }

  // ---- prime partial buffers with bias ----
  pA[wv][l] = binx;  pA[wv][l + 64] = biny;
  p1[wv][l] = b1x;   p1[wv][l + 64] = b1y;
  p2[wv][l] = b2x;   p2[wv][l + 64] = b2y;
#pragma unroll
  for (int r = 0; r < MROWS; ++r) pB[r][t + (t >> 3)] = boutv;
  __syncthreads();

#pragma unroll 1
  for (int step = 0; step < TT-1; ++step) {
    const float dti = times[step+1] - times[step];
    if (t < 64) {   // written here; all readers are >=1 barrier away in both directions
      const int r = t >> 3, c = t & 7;
      const float* cf = coeffs + (size_t)(row0 + r)*(TT*CC) + step*CC + c;
      sDx[r][c] = (cf[CC] - cf[0]) / dti;
    }

#pragma unroll 1
    for (int s = 0; s < 4; ++s) {
      // ---- P1: layer A adds (wave wv owns k in [8wv,8wv+8)) + rebias pB ----
      {
        const int kb = 8 * wv;
        float wx[8], wy[8];
#pragma unroll
        for (int j = 0; j < 8; ++j) {
          const float* wr = W_in + (kb + j) * HHD;
          wx[j] = wr[l];
          wy[j] = wr[l + 64];
        }
#pragma unroll
        for (int r = 0; r < MROWS; ++r) {
          const float4 za = *(const float4*)&sZs[r][kb];
          const float4 zb = *(const float4*)&sZs[r][kb + 4];
          const float zk[8] = {za.x, za.y, za.z, za.w, zb.x, zb.y, zb.z, zb.w};
          float a0 = 0.f, a1 = 0.f;
#pragma unroll
          for (int k = 0; k < 8; ++k) {
            a0 = fmaf(zk[k], wx[k], a0);
            a1 = fmaf(zk[k], wy[k], a1);
          }
          atomicAdd(&pA[r][l],      a0);
          atomicAdd(&pA[r][l + 64], a1);
        }
#pragma unroll
        for (int r = 0; r < MROWS; ++r) pB[r][t + (t >> 3)] = boutv;
      }
      __syncthreads();
      // ---- P2: hidden1 (reads pA, relu inline) ----
      hidden_adds_g(W_h, pA, p1, l, wv);
      __syncthreads();
      // ---- P3: hidden2 (reads p1) + rebias pA ----
      hidden_adds_g(W_h + HHD*HHD, p1, p2, l, wv);
      pA[wv][l] = binx;  pA[wv][l + 64] = biny;
      __syncthreads();
      // ---- P4: big layer: k in [16wv,16wv+16), lane cols {4l..4l+3, 256+4l..+3} ----
      {
        float acc[MROWS][8];
#pragma unroll
        for (int r = 0; r < MROWS; ++r)
#pragma unroll
          for (int c = 0; c < 8; ++c) acc[r][c] = 0.f;

        const float* wp = W_out + (size_t)(16*wv) * (HD*CC) + 4*l;
#pragma unroll
        for (int kc = 0; kc < 4; ++kc) {
          float w[4][8];                      // 32 regs, chunk-local
#pragma unroll
          for (int j = 0; j < 4; ++j) {
            const float4 a = *(const float4*)(wp + (4*kc + j)*(HD*CC));
            const float4 b = *(const float4*)(wp + (4*kc + j)*(HD*CC) + 256);
            w[j][0] = a.x; w[j][1] = a.y; w[j][2] = a.z; w[j][3] = a.w;
            w[j][4] = b.x; w[j][5] = b.y; w[j][6] = b.z; w[j][7] = b.w;
          }
          const int k0 = 16*wv + 4*kc;
#pragma unroll
          for (int r = 0; r < MROWS; ++r) {
            const float4 hv = *(const float4*)&p2[r][k0];    // broadcast
            const float hf[4] = { fmaxf(hv.x,0.f), fmaxf(hv.y,0.f),
                                  fmaxf(hv.z,0.f), fmaxf(hv.w,0.f) };
#pragma unroll
            for (int j = 0; j < 4; ++j)
#pragma unroll
              for (int c = 0; c < 8; ++c)
                acc[r][c] = fmaf(hf[j], w[j][c], acc[r][c]);
          }
        }
#pragma unroll
        for (int r = 0; r < MROWS; ++r)
#pragma unroll
          for (int c = 0; c < 8; ++c) {
            const int col = (c < 4) ? (4*l + c) : (256 + 4*l + (c - 4));
            atomicAdd(&pB[r][col + (col >> 3)], acc[r][c]);
          }
        p1[wv][l] = b1x;  p1[wv][l + 64] = b1y;
      }
      __syncthreads();
      // ---- P5: epilogue (tanh, einsum dX, RK) + rebias p2 ----
      {
        const float* pr = &pB[wv][9*l];       // cols 8l..8l+7, stride-9 = conflict-free
        const float u0 = pr[0], u1 = pr[1], u2 = pr[2], u3 = pr[3];
        const float u4 = pr[4], u5 = pr[5], u6 = pr[6], u7 = pr[7];
        const float4 d0 = *(const float4*)&sDx[wv][0];       // broadcast
        const float4 d1 = *(const float4*)&sDx[wv][4];
        float g = fast_tanh(u0)*d0.x + fast_tanh(u1)*d0.y
                + fast_tanh(u2)*d0.z + fast_tanh(u3)*d0.w
                + fast_tanh(u4)*d1.x + fast_tanh(u5)*d1.y
                + fast_tanh(u6)*d1.z + fast_tanh(u7)*d1.w;
        if (s == 0)      kacc = g;
        else if (s == 3) kacc += g;
        else             kacc += 2.0f * g;
        float zs;
        if (s == 3) {
          z0 = z0 + dti * (1.0f/6.0f) * kacc;
          zs = z0;
        } else {
          zs = z0 + ((s == 2) ? dti : 0.5f * dti) * g;
        }
        sZs[wv][l] = zs;
        p2[wv][l] = b2x;  p2[wv][l + 64] = b2y;
      }
      __syncthreads();
    } // stages
  }   // steps

  // ---- readout: logits = zT @ W_read + b_read ; loss + accuracy ----
  if (t < MROWS * OO) {
    const int r = t / OO, o = t % OO;
    float a = b_read[o];
#pragma unroll 8
    for (int k = 0; k < HD; ++k) a = fmaf(sZs[r][k], W_read[k*OO + o], a);
    sLog[r][o] = a;
  }
  __syncthreads();
  if (t < 64) {
    float lv = 0.f, cv = 0.f;
    if (t < MROWS) {
      const int r = t;
      float mx = sLog[r][0]; int am = 0;
#pragma unroll
      for (int o = 1; o < OO; ++o) { const float v = sLog[r][o]; if (v > mx) { mx = v; am = o; } }
      float se = 0.f;
#pragma unroll
      for (int o = 0; o < OO; ++o) se += expf(sLog[r][o] - mx);
      const float lse = mx + logf(se);
      const int yr = yy[row0 + r];
      lv = (lse - sLog[r][yr]) * (1.0f / (float)BB);
      cv = (am == yr) ? 1.0f : 0.0f;
    }
    lv += __shfl_xor(lv, 1); lv += __shfl_xor(lv, 2); lv += __shfl_xor(lv, 4);
    cv += __shfl_xor(cv, 1); cv += __shfl_xor(cv, 2); cv += __shfl_xor(cv, 4);
    if (t == 0) { atomicAdd(&out[0], lv); atomicAdd(&out[1], cv); }
  }
}

extern "C" void kernel_launch(void* const* d_in, const int* in_sizes, int n_in,
                              void* d_out, int out_size, void* d_ws, size_t ws_size,
                              hipStream_t stream) {
  const float* coeffs = (const float*)d_in[0];
  const int*   y      = (const int*)  d_in[1];
  const float* times  = (const float*)d_in[2];
  const float* W_init = (const float*)d_in[3];
  const float* b_init = (const float*)d_in[4];
  const float* W_in   = (const float*)d_in[5];
  const float* b_in   = (const float*)d_in[6];
  const float* W_h    = (const float*)d_in[7];
  const float* b_h    = (const float*)d_in[8];
  const float* W_out  = (const float*)d_in[9];
  const float* b_out  = (const float*)d_in[10];
  const float* W_read = (const float*)d_in[11];
  const float* b_read = (const float*)d_in[12];
  float* out = (float*)d_out;

  zero_out_k<<<1, 64, 0, stream>>>(out);   // d_out is poisoned 0xAA before every replay
  cde_main<<<BB/MROWS, NTHR, 0, stream>>>(coeffs, y, times, W_init, b_init,
                                          W_in, b_in, W_h, b_h, W_out, b_out,
                                          W_read, b_read, out);
}

// Round 5
// 30982.098 us; speedup vs baseline: 1.0051x; 1.0051x over previous
//
#include <hip/hip_runtime.h>

// Problem constants (from reference)
#define BB    2048
#define TT    100
#define CC    8
#define HD    64
#define HHD   128
#define OO    10
#define MROWS 8      // batch rows per block; grid = 256 blocks = 1 block/CU
#define NTHR  512    // 8 waves/block; waves_per_eu(2,2) -> 256-VGPR budget

__device__ __forceinline__ float fast_tanh(float x) {
  float e = __expf(2.0f * x);
  return 1.0f - 2.0f / (e + 1.0f);
}

__global__ void zero_out_k(float* o) {
  if (threadIdx.x < 2) o[threadIdx.x] = 0.0f;
}

// hidden layer k-slice: relu(pin) x wh(2 cols x 16 k, register-resident) -> ds_add pout
__device__ __forceinline__ void hidden_adds(const float2 (&wh)[16],
                                            const float (*pin)[HHD],
                                            float (*pout)[HHD],
                                            int l, int kb) {
#pragma unroll
  for (int r = 0; r < MROWS; ++r) {
    const float4 h0 = *(const float4*)&pin[r][kb+0];    // wave-uniform -> broadcast
    const float4 h1 = *(const float4*)&pin[r][kb+4];
    const float4 h2 = *(const float4*)&pin[r][kb+8];
    const float4 h3 = *(const float4*)&pin[r][kb+12];
    const float hk[16] = {
      fmaxf(h0.x,0.f), fmaxf(h0.y,0.f), fmaxf(h0.z,0.f), fmaxf(h0.w,0.f),
      fmaxf(h1.x,0.f), fmaxf(h1.y,0.f), fmaxf(h1.z,0.f), fmaxf(h1.w,0.f),
      fmaxf(h2.x,0.f), fmaxf(h2.y,0.f), fmaxf(h2.z,0.f), fmaxf(h2.w,0.f),
      fmaxf(h3.x,0.f), fmaxf(h3.y,0.f), fmaxf(h3.z,0.f), fmaxf(h3.w,0.f) };
    float a0 = 0.f, a1 = 0.f;
#pragma unroll
    for (int k = 0; k < 16; ++k) {
      a0 = fmaf(hk[k], wh[k].x, a0);
      a1 = fmaf(hk[k], wh[k].y, a1);
    }
    atomicAdd(&pout[r][l],      a0);    // ds_add_f32, 64 lanes -> 2/bank (free)
    atomicAdd(&pout[r][l + 64], a1);
  }
}

__attribute__((amdgpu_waves_per_eu(2, 2)))
__global__ void __launch_bounds__(NTHR)
cde_main(const float* __restrict__ coeffs, const int* __restrict__ yy,
         const float* __restrict__ times,
         const float* __restrict__ W_init, const float* __restrict__ b_init,
         const float* __restrict__ W_in,  const float* __restrict__ b_in,
         const float* __restrict__ W_h,   const float* __restrict__ b_h,
         const float* __restrict__ W_out, const float* __restrict__ b_out,
         const float* __restrict__ W_read,const float* __restrict__ b_read,
         float* __restrict__ out)
{
  __shared__ float sZs[MROWS][HD];        // 2KB   stage-input z
  __shared__ float pA [MROWS][HHD];       // 4KB   bias-primed partials, layer A
  __shared__ float p1 [MROWS][HHD];       // 4KB   hidden1
  __shared__ float p2 [MROWS][HHD];       // 4KB   hidden2
  __shared__ float pB [MROWS][576];       // 18KB  big layer, addr = col + (col>>3)
  __shared__ float sDx[MROWS][CC];
  __shared__ float sLog[MROWS][OO];

  const int t    = threadIdx.x;
  const int wv   = t >> 6;        // wave id 0..7 (k-slice owner; epilogue row)
  const int l    = t & 63;        // lane         (col owner; epilogue h)
  const int row0 = blockIdx.x * MROWS;

  // ---- persistent register weights: 80 floats ----
  float2 winR[8];                 // W_in k in [8wv,8wv+8), cols (l, l+64)
#pragma unroll
  for (int j = 0; j < 8; ++j) {
    const float* wr = W_in + (8*wv + j)*HHD;
    winR[j] = make_float2(wr[l], wr[l + 64]);
  }
  float2 wh1[16], wh2[16];        // W_h layers, k in [16wv,16wv+16)
#pragma unroll
  for (int j = 0; j < 16; ++j) {
    const float* w1 = W_h + (16*wv + j)*HHD;
    const float* w2 = W_h + HHD*HHD + (16*wv + j)*HHD;
    wh1[j] = make_float2(w1[l], w1[l + 64]);
    wh2[j] = make_float2(w2[l], w2[l + 64]);
  }
  const float binx = b_in[l],      biny = b_in[l + 64];
  const float b1x  = b_h[l],       b1y  = b_h[l + 64];
  const float b2x  = b_h[HHD + l], b2y  = b_h[HHD + l + 64];
  const float boutv = b_out[t];

  // ---- z0 ; thread owns (row wv, h=l) ----
  float z0, kacc = 0.f;
  {
    const float* cf = coeffs + (size_t)(row0 + wv) * (TT*CC);
    float a = b_init[l];
#pragma unroll
    for (int c = 0; c < CC; ++c) a = fmaf(cf[c], W_init[c*HD + l], a);
    z0 = a;
    sZs[wv][l] = a;
  }

  // ---- prime partial buffers with bias ----
  pA[wv][l] = binx;  pA[wv][l + 64] = biny;
  p1[wv][l] = b1x;   p1[wv][l + 64] = b1y;
  p2[wv][l] = b2x;   p2[wv][l + 64] = b2y;
#pragma unroll
  for (int r = 0; r < MROWS; ++r) pB[r][t + (t >> 3)] = boutv;
  __syncthreads();

#pragma unroll 1
  for (int step = 0; step < TT-1; ++step) {
    const float dti = times[step+1] - times[step];
    if (t < 64) {   // readers are >=1 barrier away in both directions
      const int r = t >> 3, c = t & 7;
      const float* cf = coeffs + (size_t)(row0 + r)*(TT*CC) + step*CC + c;
      sDx[r][c] = (cf[CC] - cf[0]) / dti;
    }

#pragma unroll 1
    for (int s = 0; s < 4; ++s) {
      // ---- P1: layer A adds (reads sZs raw) + rebias pB ----
      {
        const int kb = 8 * wv;
#pragma unroll
        for (int r = 0; r < MROWS; ++r) {
          const float4 za = *(const float4*)&sZs[r][kb];
          const float4 zb = *(const float4*)&sZs[r][kb + 4];
          const float zk[8] = {za.x, za.y, za.z, za.w, zb.x, zb.y, zb.z, zb.w};
          float a0 = 0.f, a1 = 0.f;
#pragma unroll
          for (int k = 0; k < 8; ++k) {
            a0 = fmaf(zk[k], winR[k].x, a0);
            a1 = fmaf(zk[k], winR[k].y, a1);
          }
          atomicAdd(&pA[r][l],      a0);
          atomicAdd(&pA[r][l + 64], a1);
        }
#pragma unroll
        for (int r = 0; r < MROWS; ++r) pB[r][t + (t >> 3)] = boutv;
      }
      __syncthreads();
      // ---- P2: hidden1 (reads pA, relu inline) ----
      hidden_adds(wh1, pA, p1, l, 16*wv);
      __syncthreads();
      // ---- P3: hidden2 (reads p1) + rebias pA ----
      hidden_adds(wh2, p1, p2, l, 16*wv);
      pA[wv][l] = binx;  pA[wv][l + 64] = biny;
      __syncthreads();
      // ---- P4: big layer, W_out STREAMED (L2-hot); wave k in [16wv,16wv+16),
      //      lane cols {4l..4l+3, 256+4l..4l+3} ----
      {
        float acc[MROWS][8];
#pragma unroll
        for (int r = 0; r < MROWS; ++r)
#pragma unroll
          for (int c = 0; c < 8; ++c) acc[r][c] = 0.f;

        const float* wp = W_out + (size_t)(16*wv) * (HD*CC) + 4*l;
#pragma unroll
        for (int kc = 0; kc < 4; ++kc) {
          float w[4][8];                      // chunk-local
#pragma unroll
          for (int j = 0; j < 4; ++j) {
            const float4 a = *(const float4*)(wp + (4*kc + j)*(HD*CC));
            const float4 b = *(const float4*)(wp + (4*kc + j)*(HD*CC) + 256);
            w[j][0] = a.x; w[j][1] = a.y; w[j][2] = a.z; w[j][3] = a.w;
            w[j][4] = b.x; w[j][5] = b.y; w[j][6] = b.z; w[j][7] = b.w;
          }
          const int k0 = 16*wv + 4*kc;
#pragma unroll
          for (int r = 0; r < MROWS; ++r) {
            const float4 hv = *(const float4*)&p2[r][k0];    // broadcast
            const float hf[4] = { fmaxf(hv.x,0.f), fmaxf(hv.y,0.f),
                                  fmaxf(hv.z,0.f), fmaxf(hv.w,0.f) };
#pragma unroll
            for (int j = 0; j < 4; ++j)
#pragma unroll
              for (int c = 0; c < 8; ++c)
                acc[r][c] = fmaf(hf[j], w[j][c], acc[r][c]);
          }
        }
#pragma unroll
        for (int r = 0; r < MROWS; ++r)
#pragma unroll
          for (int c = 0; c < 8; ++c) {
            const int col = (c < 4) ? (4*l + c) : (256 + 4*l + (c - 4));
            atomicAdd(&pB[r][col + (col >> 3)], acc[r][c]);
          }
        p1[wv][l] = b1x;  p1[wv][l + 64] = b1y;
      }
      __syncthreads();
      // ---- P5: epilogue (tanh, einsum dX, RK) + rebias p2 ----
      {
        const float* pr = &pB[wv][9*l];       // cols 8l..8l+7, stride-9 conflict-free
        const float u0 = pr[0], u1 = pr[1], u2 = pr[2], u3 = pr[3];
        const float u4 = pr[4], u5 = pr[5], u6 = pr[6], u7 = pr[7];
        const float4 d0 = *(const float4*)&sDx[wv][0];       // broadcast
        const float4 d1 = *(const float4*)&sDx[wv][4];
        float g = fast_tanh(u0)*d0.x + fast_tanh(u1)*d0.y
                + fast_tanh(u2)*d0.z + fast_tanh(u3)*d0.w
                + fast_tanh(u4)*d1.x + fast_tanh(u5)*d1.y
                + fast_tanh(u6)*d1.z + fast_tanh(u7)*d1.w;
        if (s == 0)      kacc = g;
        else if (s == 3) kacc += g;
        else             kacc += 2.0f * g;
        float zs;
        if (s == 3) {
          z0 = z0 + dti * (1.0f/6.0f) * kacc;
          zs = z0;
        } else {
          zs = z0 + ((s == 2) ? dti : 0.5f * dti) * g;
        }
        sZs[wv][l] = zs;
        p2[wv][l] = b2x;  p2[wv][l + 64] = b2y;
      }
      __syncthreads();
    } // stages
  }   // steps

  // ---- readout: logits = zT @ W_read + b_read ; loss + accuracy ----
  if (t < MROWS * OO) {
    const int r = t / OO, o = t % OO;
    float a = b_read[o];
#pragma unroll 8
    for (int k = 0; k < HD; ++k) a = fmaf(sZs[r][k], W_read[k*OO + o], a);
    sLog[r][o] = a;
  }
  __syncthreads();
  if (t < 64) {
    float lv = 0.f, cv = 0.f;
    if (t < MROWS) {
      const int r = t;
      float mx = sLog[r][0]; int am = 0;
#pragma unroll
      for (int o = 1; o < OO; ++o) { const float v = sLog[r][o]; if (v > mx) { mx = v; am = o; } }
      float se = 0.f;
#pragma unroll
      for (int o = 0; o < OO; ++o) se += expf(sLog[r][o] - mx);
      const float lse = mx + logf(se);
      const int yr = yy[row0 + r];
      lv = (lse - sLog[r][yr]) * (1.0f / (float)BB);
      cv = (am == yr) ? 1.0f : 0.0f;
    }
    lv += __shfl_xor(lv, 1); lv += __shfl_xor(lv, 2); lv += __shfl_xor(lv, 4);
    cv += __shfl_xor(cv, 1); cv += __shfl_xor(cv, 2); cv += __shfl_xor(cv, 4);
    if (t == 0) { atomicAdd(&out[0], lv); atomicAdd(&out[1], cv); }
  }
}

extern "C" void kernel_launch(void* const* d_in, const int* in_sizes, int n_in,
                              void* d_out, int out_size, void* d_ws, size_t ws_size,
                              hipStream_t stream) {
  const float* coeffs = (const float*)d_in[0];
  const int*   y      = (const int*)  d_in[1];
  const float* times  = (const float*)d_in[2];
  const float* W_init = (const float*)d_in[3];
  const float* b_init = (const float*)d_in[4];
  const float* W_in   = (const float*)d_in[5];
  const float* b_in   = (const float*)d_in[6];
  const float* W_h    = (const float*)d_in[7];
  const float* b_h    = (const float*)d_in[8];
  const float* W_out  = (const float*)d_in[9];
  const float* b_out  = (const float*)d_in[10];
  const float* W_read = (const float*)d_in[11];
  const float* b_read = (const float*)d_in[12];
  float* out = (float*)d_out;

  zero_out_k<<<1, 64, 0, stream>>>(out);   // d_out is poisoned 0xAA before every replay
  cde_main<<<BB/MROWS, NTHR, 0, stream>>>(coeffs, y, times, W_init, b_init,
                                          W_in, b_in, W_h, b_h, W_out, b_out,
                                          W_read, b_read, out);
}

// Round 6
// 18497.845 us; speedup vs baseline: 1.6834x; 1.6749x over previous
//
#include <hip/hip_runtime.h>

// Problem constants (from reference)
#define BB    2048
#define TT    100
#define CC    8
#define HD    64
#define HHD   128
#define OO    10
#define MROWS 8      // batch rows per block; grid = 256 blocks = 1 block/CU
#define NTHR  512    // 8 waves/block; design fits the 128-VGPR budget (audited)

__device__ __forceinline__ float fast_tanh(float x) {
  float e = __expf(2.0f * x);
  return 1.0f - 2.0f / (e + 1.0f);
}

__global__ void zero_out_k(float* o) {
  if (threadIdx.x < 2) o[threadIdx.x] = 0.0f;
}

// Hidden layer slice: rows [rb,rb+4), k in [kb,kb+32), lane cols (l, l+64).
// Weights streamed from global (L2-hot) in 16k chunks; relu applied on read.
// Live regs ~75: wx/wy 32 + hk 16 + acc 8 + overhead.
__device__ __forceinline__ void hidden_layer(const float* __restrict__ Wg,
                                             const float (*pin)[HHD],
                                             float (*pout)[HHD],
                                             int l, int kb, int rb) {
  float a0[4] = {0.f,0.f,0.f,0.f};
  float a1[4] = {0.f,0.f,0.f,0.f};
#pragma unroll
  for (int h = 0; h < 2; ++h) {
    float wx[16], wy[16];                       // chunk-local, dies at loop end
#pragma unroll
    for (int j = 0; j < 16; ++j) {
      const float* wr = Wg + (kb + 16*h + j) * HHD;
      wx[j] = wr[l];                            // 256B coalesced per wave
      wy[j] = wr[l + 64];
    }
#pragma unroll
    for (int rr = 0; rr < 4; ++rr) {
      const float* pr = &pin[rb + rr][kb + 16*h];
      const float4 h0 = *(const float4*)(pr);       // wave-uniform -> broadcast
      const float4 h1 = *(const float4*)(pr + 4);
      const float4 h2 = *(const float4*)(pr + 8);
      const float4 h3 = *(const float4*)(pr + 12);
      const float hk[16] = {
        fmaxf(h0.x,0.f), fmaxf(h0.y,0.f), fmaxf(h0.z,0.f), fmaxf(h0.w,0.f),
        fmaxf(h1.x,0.f), fmaxf(h1.y,0.f), fmaxf(h1.z,0.f), fmaxf(h1.w,0.f),
        fmaxf(h2.x,0.f), fmaxf(h2.y,0.f), fmaxf(h2.z,0.f), fmaxf(h2.w,0.f),
        fmaxf(h3.x,0.f), fmaxf(h3.y,0.f), fmaxf(h3.z,0.f), fmaxf(h3.w,0.f) };
#pragma unroll
      for (int k = 0; k < 16; ++k) {
        a0[rr] = fmaf(hk[k], wx[k], a0[rr]);
        a1[rr] = fmaf(hk[k], wy[k], a1[rr]);
      }
    }
  }
#pragma unroll
  for (int rr = 0; rr < 4; ++rr) {              // ds_add_f32, 2 lanes/bank = free
    atomicAdd(&pout[rb + rr][l],      a0[rr]);
    atomicAdd(&pout[rb + rr][l + 64], a1[rr]);
  }
}

__global__ void __launch_bounds__(NTHR)
cde_main(const float* __restrict__ coeffs, const int* __restrict__ yy,
         const float* __restrict__ times,
         const float* __restrict__ W_init, const float* __restrict__ b_init,
         const float* __restrict__ W_in,  const float* __restrict__ b_in,
         const float* __restrict__ W_h,   const float* __restrict__ b_h,
         const float* __restrict__ W_out, const float* __restrict__ b_out,
         const float* __restrict__ W_read,const float* __restrict__ b_read,
         float* __restrict__ out)
{
  __shared__ float sZs[MROWS][HD];        // 2KB   stage-input z
  __shared__ float pA [MROWS][HHD];       // 4KB   bias-primed partials, layer A
  __shared__ float p1 [MROWS][HHD];       // 4KB   hidden1
  __shared__ float p2 [MROWS][HHD];       // 4KB   hidden2
  __shared__ float pB [MROWS][576];       // 18KB  big layer, addr = col + (col>>3)
  __shared__ float sDx[MROWS][CC];
  __shared__ float sLog[MROWS][OO];

  const int t    = threadIdx.x;
  const int wv   = t >> 6;        // wave id 0..7
  const int l    = t & 63;        // lane
  const int row0 = blockIdx.x * MROWS;
  // P1-P3 mapping: k-slice q = wv&3, row-group rb = 4*(wv>>2)
  const int q    = wv & 3;
  const int rb   = 4 * (wv >> 2);
  // P4 mapping: k-slice ksl = wv&3 (32k), col-half = wv>>2 (256 cols, 4/lane)
  const int colb = 256 * (wv >> 2) + 4 * l;

  // tiny persistent scalars only (~25 regs total incl addressing)
  const float binx = b_in[l],      biny = b_in[l + 64];
  const float b1x  = b_h[l],       b1y  = b_h[l + 64];
  const float b2x  = b_h[HHD + l], b2y  = b_h[HHD + l + 64];
  const float boutv = b_out[t];

  // ---- z0 ; thread owns (row wv, h=l) for RK state ----
  float z0, kacc = 0.f;
  {
    const float* cf = coeffs + (size_t)(row0 + wv) * (TT*CC);
    float a = b_init[l];
#pragma unroll
    for (int c = 0; c < CC; ++c) a = fmaf(cf[c], W_init[c*HD + l], a);
    z0 = a;
    sZs[wv][l] = a;
  }

  // ---- prime partial buffers with bias ----
  pA[wv][l] = binx;  pA[wv][l + 64] = biny;
  p1[wv][l] = b1x;   p1[wv][l + 64] = b1y;
  p2[wv][l] = b2x;   p2[wv][l + 64] = b2y;
#pragma unroll
  for (int r = 0; r < MROWS; ++r) pB[r][t + (t >> 3)] = boutv;
  __syncthreads();

#pragma unroll 1
  for (int step = 0; step < TT-1; ++step) {
    const float dti = times[step+1] - times[step];
    if (t < 64) {   // sDx readers (P5) are barrier-separated both directions
      const int r = t >> 3, c = t & 7;
      const float* cf = coeffs + (size_t)(row0 + r)*(TT*CC) + step*CC + c;
      sDx[r][c] = (cf[CC] - cf[0]) / dti;
    }

#pragma unroll 1
    for (int s = 0; s < 4; ++s) {
      // ---- P1: layer A. rows [rb,rb+4), k in [16q,16q+16). + prime pB ----
      {
        const int kb = 16 * q;
        float wx[16], wy[16];
#pragma unroll
        for (int j = 0; j < 16; ++j) {
          const float* wr = W_in + (kb + j) * HHD;
          wx[j] = wr[l];
          wy[j] = wr[l + 64];
        }
#pragma unroll
        for (int rr = 0; rr < 4; ++rr) {
          const float* zr = &sZs[rb + rr][kb];
          const float4 za = *(const float4*)(zr);
          const float4 zb = *(const float4*)(zr + 4);
          const float4 zc = *(const float4*)(zr + 8);
          const float4 zd = *(const float4*)(zr + 12);
          const float zk[16] = {za.x, za.y, za.z, za.w, zb.x, zb.y, zb.z, zb.w,
                                zc.x, zc.y, zc.z, zc.w, zd.x, zd.y, zd.z, zd.w};
          float a0 = 0.f, a1 = 0.f;
#pragma unroll
          for (int k = 0; k < 16; ++k) {
            a0 = fmaf(zk[k], wx[k], a0);
            a1 = fmaf(zk[k], wy[k], a1);
          }
          atomicAdd(&pA[rb + rr][l],      a0);
          atomicAdd(&pA[rb + rr][l + 64], a1);
        }
#pragma unroll
        for (int r = 0; r < MROWS; ++r) pB[r][t + (t >> 3)] = boutv;
      }
      __syncthreads();
      // ---- P2: hidden1 (reads pA, relu inline) ----
      hidden_layer(W_h, pA, p1, l, 32*q, rb);
      __syncthreads();
      // ---- P3: hidden2 (reads p1) + rebias pA ----
      hidden_layer(W_h + HHD*HHD, p1, p2, l, 32*q, rb);
      pA[wv][l] = binx;  pA[wv][l + 64] = biny;
      __syncthreads();
      // ---- P4: big layer. k in [32ksl,32ksl+32), cols colb..colb+3. + rebias p1 ----
      {
        float acc[MROWS][4];
#pragma unroll
        for (int r = 0; r < MROWS; ++r)
#pragma unroll
          for (int c = 0; c < 4; ++c) acc[r][c] = 0.f;

        const float* wp = W_out + (size_t)(32*q) * (HD*CC) + colb;
#pragma unroll
        for (int kc = 0; kc < 8; ++kc) {
          float4 w4[4];                         // 16 regs, chunk-local
#pragma unroll
          for (int j = 0; j < 4; ++j)
            w4[j] = *(const float4*)(wp + (4*kc + j)*(HD*CC));   // 1KB/wave coalesced
          const int k0 = 32*q + 4*kc;
#pragma unroll
          for (int r = 0; r < MROWS; ++r) {
            const float4 hv = *(const float4*)&p2[r][k0];        // broadcast
            const float hf[4] = { fmaxf(hv.x,0.f), fmaxf(hv.y,0.f),
                                  fmaxf(hv.z,0.f), fmaxf(hv.w,0.f) };
#pragma unroll
            for (int j = 0; j < 4; ++j) {
              acc[r][0] = fmaf(hf[j], w4[j].x, acc[r][0]);
              acc[r][1] = fmaf(hf[j], w4[j].y, acc[r][1]);
              acc[r][2] = fmaf(hf[j], w4[j].z, acc[r][2]);
              acc[r][3] = fmaf(hf[j], w4[j].w, acc[r][3]);
            }
          }
        }
#pragma unroll
        for (int r = 0; r < MROWS; ++r)
#pragma unroll
          for (int c = 0; c < 4; ++c) {
            const int col = colb + c;
            atomicAdd(&pB[r][col + (col >> 3)], acc[r][c]);
          }
        p1[wv][l] = b1x;  p1[wv][l + 64] = b1y;
      }
      __syncthreads();
      // ---- P5: epilogue (tanh, einsum dX, RK) + rebias p2 ----
      {
        const float* pr = &pB[wv][9*l];       // cols 8l..8l+7, stride-9 conflict-free
        const float u0 = pr[0], u1 = pr[1], u2 = pr[2], u3 = pr[3];
        const float u4 = pr[4], u5 = pr[5], u6 = pr[6], u7 = pr[7];
        const float4 d0 = *(const float4*)&sDx[wv][0];   // broadcast
        const float4 d1 = *(const float4*)&sDx[wv][4];
        float g = fast_tanh(u0)*d0.x + fast_tanh(u1)*d0.y
                + fast_tanh(u2)*d0.z + fast_tanh(u3)*d0.w
                + fast_tanh(u4)*d1.x + fast_tanh(u5)*d1.y
                + fast_tanh(u6)*d1.z + fast_tanh(u7)*d1.w;
        if (s == 0)      kacc = g;
        else if (s == 3) kacc += g;
        else             kacc += 2.0f * g;
        float zs;
        if (s == 3) {
          z0 = z0 + dti * (1.0f/6.0f) * kacc;
          zs = z0;
        } else {
          zs = z0 + ((s == 2) ? dti : 0.5f * dti) * g;
        }
        sZs[wv][l] = zs;
        p2[wv][l] = b2x;  p2[wv][l + 64] = b2y;
      }
      __syncthreads();
    } // stages
  }   // steps

  // ---- readout: logits = zT @ W_read + b_read ; loss + accuracy ----
  if (t < MROWS * OO) {
    const int r = t / OO, o = t % OO;
    float a = b_read[o];
#pragma unroll 8
    for (int k = 0; k < HD; ++k) a = fmaf(sZs[r][k], W_read[k*OO + o], a);
    sLog[r][o] = a;
  }
  __syncthreads();
  if (t < 64) {
    float lv = 0.f, cv = 0.f;
    if (t < MROWS) {
      const int r = t;
      float mx = sLog[r][0]; int am = 0;
#pragma unroll
      for (int o = 1; o < OO; ++o) { const float v = sLog[r][o]; if (v > mx) { mx = v; am = o; } }
      float se = 0.f;
#pragma unroll
      for (int o = 0; o < OO; ++o) se += expf(sLog[r][o] - mx);
      const float lse = mx + logf(se);
      const int yr = yy[row0 + r];
      lv = (lse - sLog[r][yr]) * (1.0f / (float)BB);
      cv = (am == yr) ? 1.0f : 0.0f;
    }
    lv += __shfl_xor(lv, 1); lv += __shfl_xor(lv, 2); lv += __shfl_xor(lv, 4);
    cv += __shfl_xor(cv, 1); cv += __shfl_xor(cv, 2); cv += __shfl_xor(cv, 4);
    if (t == 0) { atomicAdd(&out[0], lv); atomicAdd(&out[1], cv); }
  }
}

extern "C" void kernel_launch(void* const* d_in, const int* in_sizes, int n_in,
                              void* d_out, int out_size, void* d_ws, size_t ws_size,
                              hipStream_t stream) {
  const float* coeffs = (const float*)d_in[0];
  const int*   y      = (const int*)  d_in[1];
  const float* times  = (const float*)d_in[2];
  const float* W_init = (const float*)d_in[3];
  const float* b_init = (const float*)d_in[4];
  const float* W_in   = (const float*)d_in[5];
  const float* b_in   = (const float*)d_in[6];
  const float* W_h    = (const float*)d_in[7];
  const float* b_h    = (const float*)d_in[8];
  const float* W_out  = (const float*)d_in[9];
  const float* b_out  = (const float*)d_in[10];
  const float* W_read = (const float*)d_in[11];
  const float* b_read = (const float*)d_in[12];
  float* out = (float*)d_out;

  zero_out_k<<<1, 64, 0, stream>>>(out);   // d_out is poisoned 0xAA before every replay
  cde_main<<<BB/MROWS, NTHR, 0, stream>>>(coeffs, y, times, W_init, b_init,
                                          W_in, b_in, W_h, b_h, W_out, b_out,
                                          W_read, b_read, out);
}